// Round 5
// baseline (235.912 us; speedup 1.0000x reference)
//
#include <hip/hip_runtime.h>

#define H 384
#define W 384
#define HWSZ (H * W)
#define NB 16
#define ND 2048
#define DD 256

// workspace byte offsets (all 256-aligned)
#define OFF_RESP  256
#define OFF_CVAL  9437440
#define OFF_CPOS  9584896
#define OFF_DESCB 9732352     // fp8 descriptors: 16*2048*256 = 8.4 MB
#define OFF_INV   26509568
#define OFF_PSOFT 26640640    // 576 floats
#define OFF_PGEMM 26643200    // 2176 floats
#define OFF_PCORN 26652160    // 16 floats

__device__ __forceinline__ int clampi(int v) { return v < 0 ? 0 : (v > 383 ? 383 : v); }
__device__ __forceinline__ int refl(int v) { return v < 0 ? -v : (v >= 384 ? 766 - v : v); }

// fp32 -> OCP e4m3fn with RNE (software; subnormals exact, clamp to 448).
// Layout: [s:1][eeee:4][mmm:3] -> s<<7 | e<<3 | m.  (R4 bug: e<<4 corrupted
// the byte — exponent overflowed into the sign bit; found via error-magnitude
// arithmetic: absmax 236 == pcos inflated ~4096x == exponent doubled.)
__device__ __forceinline__ unsigned f2e4m3(float x) {
  float a = fabsf(x);
  unsigned s = (__float_as_uint(x) >> 31) << 7;
  if (a >= 448.f) return s | 0x7E;
  if (a < 0.015625f) {                    // subnormal region, unit 2^-9
    int m = (int)rintf(a * 512.f);        // RNE; m==8 -> 0x08 == 2^-6 (correct)
    return s | (unsigned)m;
  }
  unsigned u = __float_as_uint(a);
  u += 0x7FFFF + ((u >> 20) & 1);         // RNE to 3 mantissa bits
  unsigned e = (u >> 23) - 120;           // rebias 127->7, e in [1,15]
  unsigned m = (u >> 20) & 7;
  return s | (e << 3) | m;
}

// ---------------------------------------------------------------------------
// Fused: grayscale -> sobel(edge pad) -> products -> separable 7x7 gauss
// (reflect pad) -> GFTT min-eigenvalue response. One 32x32 output tile/block.
// ---------------------------------------------------------------------------
__global__ __launch_bounds__(256) void resp_kernel(const float* __restrict__ imgs,
                                                   float* __restrict__ resp) {
  const float GW[7] = {0.0044330482f, 0.0540055826f, 0.2420362294f, 0.3990502160f,
                       0.2420362294f, 0.0540055826f, 0.0044330482f};
  __shared__ float gl[40][41];
  __shared__ float p0[38][39], p1[38][39], p2[38][39];
  __shared__ float t0[38][33], t1[38][33], t2[38][33];

  int bid = blockIdx.x;
  int b = bid / 144;
  int t = bid % 144;
  int Y0 = (t / 12) * 32, X0 = (t % 12) * 32;
  const float* ib = imgs + (size_t)b * 3 * HWSZ;

  for (int i = threadIdx.x; i < 1600; i += 256) {
    int r = i / 40, c = i % 40;
    int gy = clampi(Y0 - 4 + r), gx = clampi(X0 - 4 + c);
    const float* p = ib + gy * W + gx;
    gl[r][c] = 0.299f * p[0] + 0.587f * p[HWSZ] + 0.114f * p[2 * HWSZ];
  }
  __syncthreads();

  for (int i = threadIdx.x; i < 1444; i += 256) {
    int r = i / 38, c = i % 38;
    int py = refl(Y0 - 3 + r), px = refl(X0 - 3 + c);
    int ym = clampi(py - 1) - (Y0 - 4), y0 = py - (Y0 - 4), yp = clampi(py + 1) - (Y0 - 4);
    int xm = clampi(px - 1) - (X0 - 4), x0 = px - (X0 - 4), xp = clampi(px + 1) - (X0 - 4);
    float a = gl[ym][xm], bb = gl[ym][x0], cc = gl[ym][xp];
    float d = gl[y0][xm], e = gl[y0][xp];
    float f = gl[yp][xm], g = gl[yp][x0], h = gl[yp][xp];
    float dx = 0.125f * ((cc - a) + 2.f * (e - d) + (h - f));
    float dy = 0.125f * ((f - a) + 2.f * (g - bb) + (h - cc));
    p0[r][c] = dx * dx;
    p1[r][c] = dy * dy;
    p2[r][c] = dx * dy;
  }
  __syncthreads();

  for (int i = threadIdx.x; i < 1216; i += 256) {
    int r = i / 32, c = i % 32;
    float s0 = 0.f, s1 = 0.f, s2 = 0.f;
#pragma unroll
    for (int j = 0; j < 7; j++) {
      s0 += GW[j] * p0[r][c + j];
      s1 += GW[j] * p1[r][c + j];
      s2 += GW[j] * p2[r][c + j];
    }
    t0[r][c] = s0; t1[r][c] = s1; t2[r][c] = s2;
  }
  __syncthreads();

  for (int i = threadIdx.x; i < 1024; i += 256) {
    int r = i / 32, c = i % 32;
    float s0 = 0.f, s1 = 0.f, s2 = 0.f;
#pragma unroll
    for (int j = 0; j < 7; j++) {
      s0 += GW[j] * t0[r + j][c];
      s1 += GW[j] * t1[r + j][c];
      s2 += GW[j] * t2[r + j][c];
    }
    float tr = s0 + s1;
    float det = s0 * s1 - s2 * s2;
    float disc = tr * tr - 4.f * det;
    float rv = 0.5f * (tr - sqrtf(fabsf(disc)));
    resp[(size_t)b * HWSZ + (Y0 + r) * W + (X0 + c)] = rv;
  }
}

// ---------------------------------------------------------------------------
// 5x5 NMS (-inf border) + per-8x8-block max candidate extraction.
// ---------------------------------------------------------------------------
__global__ __launch_bounds__(256) void nms_kernel(const float* __restrict__ resp,
                                                  float* __restrict__ cval,
                                                  unsigned* __restrict__ cpos) {
  __shared__ float rl[68][69];
  __shared__ float nl[64][65];
  int bid = blockIdx.x;
  int b = bid / 36;
  int t = bid % 36;
  int Y0 = (t / 6) * 64, X0 = (t % 6) * 64;
  const float* rb = resp + (size_t)b * HWSZ;

  for (int i = threadIdx.x; i < 68 * 68; i += 256) {
    int r = i / 68, c = i % 68;
    int gy = Y0 - 2 + r, gx = X0 - 2 + c;
    float v = -INFINITY;
    if (gy >= 0 && gy < H && gx >= 0 && gx < W) v = rb[gy * W + gx];
    rl[r][c] = v;
  }
  __syncthreads();

  for (int i = threadIdx.x; i < 4096; i += 256) {
    int r = i / 64, c = i % 64;
    float m = -INFINITY;
#pragma unroll
    for (int dr = 0; dr < 5; dr++)
#pragma unroll
      for (int dc = 0; dc < 5; dc++) m = fmaxf(m, rl[r + dr][c + dc]);
    float v = rl[r + 2][c + 2];
    nl[r][c] = (v == m) ? v : 0.f;
  }
  __syncthreads();

  if (threadIdx.x < 64) {
    int bi = threadIdx.x / 8, bj = threadIdx.x % 8;
    float bv = 0.f;
    unsigned bp = 0;
    for (int rr = 0; rr < 8; rr++)
      for (int cc = 0; cc < 8; cc++) {
        float v = nl[bi * 8 + rr][bj * 8 + cc];
        if (v > bv) { bv = v; bp = (unsigned)((Y0 + bi * 8 + rr) * W + (X0 + bj * 8 + cc)); }
      }
    int ci = b * 2304 + (Y0 / 8 + bi) * 48 + (X0 / 8 + bj);
    cval[ci] = bv;
    cpos[ci] = bp;
  }
}

// ---------------------------------------------------------------------------
// Per-batch top-200 via byte-wise radix-select.
// ---------------------------------------------------------------------------
__global__ __launch_bounds__(256) void topk_kernel(const float* __restrict__ cval,
                                                   const unsigned* __restrict__ cpos,
                                                   const float* __restrict__ sd,
                                                   float* __restrict__ pcorn) {
  __shared__ int hist[256];
  __shared__ int pick[2];
  __shared__ unsigned eqpos[256];
  __shared__ int eqcnt;
  __shared__ float rf[4];
  __shared__ int ri[4];

  int b = blockIdx.x;
  int t = threadIdx.x;
  int lane = t & 63;

  unsigned bits[9], pos[9];
#pragma unroll
  for (int q = 0; q < 9; q++) {
    int i = t + q * 256;
    unsigned vb = 0, p = 0;
    if (i < 2304) {
      float v = cval[b * 2304 + i];
      if (v > 0.f) { vb = __float_as_uint(v); p = cpos[b * 2304 + i]; }
    }
    bits[q] = vb; pos[q] = p;
  }

  int P = 0;
#pragma unroll
  for (int q = 0; q < 9; q++) P += (bits[q] != 0u);
  for (int off = 32; off; off >>= 1) P += __shfl_down(P, off, 64);
  if (lane == 0) ri[t >> 6] = P;
  __syncthreads();
  int Ptot = ri[0] + ri[1] + ri[2] + ri[3];
  if (Ptot == 0) { if (t == 0) pcorn[b] = 0.f; return; }
  int K = Ptot < 200 ? Ptot : 200;

  unsigned prefix = 0;
  int krem = K;
  for (int shift = 24; shift >= 0; shift -= 8) {
    hist[t] = 0;
    __syncthreads();
#pragma unroll
    for (int q = 0; q < 9; q++) {
      if (bits[q] != 0u &&
          (shift == 24 || (bits[q] >> (shift + 8)) == (prefix >> (shift + 8))))
        atomicAdd(&hist[(bits[q] >> shift) & 0xFF], 1);
    }
    __syncthreads();
    if (t < 64) {
      int h0 = hist[4 * t], h1 = hist[4 * t + 1], h2 = hist[4 * t + 2], h3 = hist[4 * t + 3];
      int tot = h0 + h1 + h2 + h3;
      int acc = tot;
      for (int d = 1; d < 64; d <<= 1) {
        int o = __shfl_down(acc, d, 64);
        if (t + d < 64) acc += o;
      }
      int excl = acc - tot;
      int G3 = excl, G2 = excl + h3, G1 = excl + h3 + h2, G0 = excl + h3 + h2 + h1;
      if (G0 < krem && G0 + h0 >= krem) { pick[0] = 4 * t;     pick[1] = G0; }
      if (G1 < krem && G1 + h1 >= krem) { pick[0] = 4 * t + 1; pick[1] = G1; }
      if (G2 < krem && G2 + h2 >= krem) { pick[0] = 4 * t + 2; pick[1] = G2; }
      if (G3 < krem && G3 + h3 >= krem) { pick[0] = 4 * t + 3; pick[1] = G3; }
    }
    __syncthreads();
    prefix |= ((unsigned)pick[0]) << shift;
    krem -= pick[1];
    __syncthreads();
  }

  if (t == 0) eqcnt = 0;
  __syncthreads();
  float s = 0.f;
#pragma unroll
  for (int q = 0; q < 9; q++) {
    if (bits[q] > prefix) s += sd[(size_t)b * HWSZ + pos[q]];
    else if (bits[q] != 0u && bits[q] == prefix) {
      int idx = atomicAdd(&eqcnt, 1);
      if (idx < 256) eqpos[idx] = pos[q];
    }
  }
  __syncthreads();
  int m = eqcnt;
  if (m <= krem) {
    if (t < m) s += sd[(size_t)b * HWSZ + eqpos[t]];
  } else {
    int mm = m < 256 ? m : 256;
    if (t < mm) {
      unsigned p = eqpos[t];
      int rank = 0;
      for (int u = 0; u < mm; u++) rank += (eqpos[u] < p);
      if (rank < krem) s += sd[(size_t)b * HWSZ + p];
    }
  }
  for (int off = 32; off; off >>= 1) s += __shfl_down(s, off, 64);
  if (lane == 0) rf[t >> 6] = s;
  __syncthreads();
  if (t == 0) pcorn[b] = rf[0] + rf[1] + rf[2] + rf[3];
}

// ---------------------------------------------------------------------------
// Sum of softplus(scores_dense) -> per-block partials.
// ---------------------------------------------------------------------------
__global__ __launch_bounds__(256) void softplus_kernel(const float4* __restrict__ sd,
                                                       float* __restrict__ psoft) {
  __shared__ float r4[4];
  float s = 0.f;
  int base = blockIdx.x * 256 + threadIdx.x;
#pragma unroll
  for (int it = 0; it < 4; it++) {
    float4 v = sd[base + it * 147456];
    s += fmaxf(v.x, 0.f) + log1pf(expf(-fabsf(v.x))) +
         fmaxf(v.y, 0.f) + log1pf(expf(-fabsf(v.y))) +
         fmaxf(v.z, 0.f) + log1pf(expf(-fabsf(v.z))) +
         fmaxf(v.w, 0.f) + log1pf(expf(-fabsf(v.w)));
  }
  for (int off = 32; off; off >>= 1) s += __shfl_down(s, off, 64);
  if ((threadIdx.x & 63) == 0) r4[threadIdx.x >> 6] = s;
  __syncthreads();
  if (threadIdx.x == 0) psoft[blockIdx.x] = r4[0] + r4[1] + r4[2] + r4[3];
}

// ---------------------------------------------------------------------------
// Descriptor prep: fp32 -> fp8 e4m3 + per-row inverse norm (fp32 norms).
// One wave per 256-float row; each lane converts 4 floats -> packed uint.
// ---------------------------------------------------------------------------
__global__ __launch_bounds__(256) void prep_desc_kernel(const float* __restrict__ desc,
                                                        unsigned char* __restrict__ descF8,
                                                        float* __restrict__ invn) {
  int wave = threadIdx.x >> 6, lane = threadIdx.x & 63;
  int row = blockIdx.x * 4 + wave;
  const float4* src = (const float4*)(desc + (size_t)row * DD);
  float4 v = src[lane];
  unsigned pk = f2e4m3(v.x) | (f2e4m3(v.y) << 8) | (f2e4m3(v.z) << 16) | (f2e4m3(v.w) << 24);
  ((unsigned*)(descF8 + (size_t)row * DD))[lane] = pk;
  float ss = v.x * v.x + v.y * v.y + v.z * v.z + v.w * v.w;
  for (int off = 32; off; off >>= 1) ss += __shfl_down(ss, off, 64);
  if (lane == 0) invn[row] = 1.f / fmaxf(sqrtf(ss), 1e-4f);
}

// ---------------------------------------------------------------------------
// Symmetric batched GEMM (A·A^T) in fp8 e4m3 with fused relu-sum epilogue.
// 128x128 tiles, BK=128 (2 K-iterations), 16x16x32 fp8 MFMA,
// global_load_lds width-16 staging. Upper-triangular tile pairs only.
// ---------------------------------------------------------------------------
typedef float f32x4 __attribute__((ext_vector_type(4)));

__device__ __forceinline__ void load_lds16(const void* g, void* l) {
  __builtin_amdgcn_global_load_lds((const __attribute__((address_space(1))) void*)g,
                                   (__attribute__((address_space(3))) void*)l, 16, 0, 0);
}

__global__ __launch_bounds__(256) void gemm_relu_kernel(const unsigned char* __restrict__ descF8,
                                                        const float* __restrict__ invn,
                                                        float* __restrict__ pgemm) {
  int bx = blockIdx.x;
  int batch = bx / 136;
  int rem = bx % 136;
  int ti = 0, rowlen = 16;
  while (rem >= rowlen) { rem -= rowlen; rowlen--; ti++; }
  int tj = ti + rem;

  const unsigned char* Ab = descF8 + (size_t)batch * ND * DD;
  const float* inv = invn + batch * ND;
  int I0 = ti * 128, J0 = tj * 128;

  __shared__ char lA[128 * 128];   // 16 KB: 128 rows x 128 bytes (BK=128 fp8)
  __shared__ char lB[128 * 128];
  __shared__ float r4[4];

  int tid = threadIdx.x;
  int wave = tid >> 6, lane = tid & 63;
  int rm = lane & 15, kq = lane >> 4;
  int wr = wave >> 1, wc = wave & 1;
  int lrow = lane >> 3, lcolb = (lane & 7) * 16;

  f32x4 accf[4][4];
#pragma unroll
  for (int m = 0; m < 4; m++)
#pragma unroll
    for (int n = 0; n < 4; n++) accf[m][n] = (f32x4){0.f, 0.f, 0.f, 0.f};

  for (int k0 = 0; k0 < DD; k0 += 128) {
#pragma unroll
    for (int q = 0; q < 4; q++) {
      int chunk = wave * 4 + q;   // covers rows chunk*8 .. chunk*8+7 (128B each)
      load_lds16(Ab + (size_t)(I0 + chunk * 8 + lrow) * DD + k0 + lcolb, lA + chunk * 1024);
      load_lds16(Ab + (size_t)(J0 + chunk * 8 + lrow) * DD + k0 + lcolb, lB + chunk * 1024);
    }
    __syncthreads();
#pragma unroll
    for (int kk = 0; kk < 128; kk += 32) {
      long af[4], bfr[4];
      int koff = kk + kq * 8;
#pragma unroll
      for (int m = 0; m < 4; m++)
        af[m] = *reinterpret_cast<const long*>(lA + (wr * 64 + m * 16 + rm) * 128 + koff);
#pragma unroll
      for (int n = 0; n < 4; n++)
        bfr[n] = *reinterpret_cast<const long*>(lB + (wc * 64 + n * 16 + rm) * 128 + koff);
#pragma unroll
      for (int m = 0; m < 4; m++)
#pragma unroll
        for (int n = 0; n < 4; n++)
          accf[m][n] = __builtin_amdgcn_mfma_f32_16x16x32_fp8_fp8(af[m], bfr[n], accf[m][n], 0, 0, 0);
    }
    __syncthreads();
  }

  float wgt = (ti == tj) ? 1.f : 2.f;
  float invC[4];
#pragma unroll
  for (int n = 0; n < 4; n++) invC[n] = inv[J0 + wc * 64 + n * 16 + rm];
  float psum = 0.f;
#pragma unroll
  for (int m = 0; m < 4; m++) {
#pragma unroll
    for (int r = 0; r < 4; r++) {
      float invR = inv[I0 + wr * 64 + m * 16 + kq * 4 + r];
#pragma unroll
      for (int n = 0; n < 4; n++) psum += fmaxf(accf[m][n][r] * invR * invC[n], 0.f);
    }
  }
  psum *= wgt;
  for (int off = 32; off; off >>= 1) psum += __shfl_down(psum, off, 64);
  if (lane == 0) r4[wave] = psum;
  __syncthreads();
  if (tid == 0) pgemm[bx] = r4[0] + r4[1] + r4[2] + r4[3];
}

// ---------------------------------------------------------------------------
// Final reduction over all partial arrays -> out[0].
// ---------------------------------------------------------------------------
__global__ __launch_bounds__(256) void finalize_kernel(const float* __restrict__ psoft,
                                                       const float* __restrict__ pcorn,
                                                       const float* __restrict__ pgemm,
                                                       float* __restrict__ out) {
  __shared__ float r4[4];
  float bce = 0.f;
  for (int i = threadIdx.x; i < 576; i += 256) bce += psoft[i];
  if (threadIdx.x < 16) bce -= pcorn[threadIdx.x];
  float g = 0.f;
  for (int i = threadIdx.x; i < 2176; i += 256) g += pgemm[i];
  float t = bce * (1.f / 2359296.f) + g * (1.f / 67108864.f);
  for (int off = 32; off; off >>= 1) t += __shfl_down(t, off, 64);
  if ((threadIdx.x & 63) == 0) r4[threadIdx.x >> 6] = t;
  __syncthreads();
  if (threadIdx.x == 0) out[0] = r4[0] + r4[1] + r4[2] + r4[3];
}

extern "C" void kernel_launch(void* const* d_in, const int* in_sizes, int n_in,
                              void* d_out, int out_size, void* d_ws, size_t ws_size,
                              hipStream_t stream) {
  (void)in_sizes; (void)n_in; (void)out_size; (void)ws_size;
  const float* desc = (const float*)d_in[0];
  const float* sd = (const float*)d_in[2];
  const float* imgs = (const float*)d_in[3];
  float* out = (float*)d_out;

  char* w = (char*)d_ws;
  float* resp = (float*)(w + OFF_RESP);
  float* cval = (float*)(w + OFF_CVAL);
  unsigned* cpos = (unsigned*)(w + OFF_CPOS);
  unsigned char* descF8 = (unsigned char*)(w + OFF_DESCB);
  float* invn = (float*)(w + OFF_INV);
  float* psoft = (float*)(w + OFF_PSOFT);
  float* pgemm = (float*)(w + OFF_PGEMM);
  float* pcorn = (float*)(w + OFF_PCORN);

  resp_kernel<<<2304, 256, 0, stream>>>(imgs, resp);
  nms_kernel<<<576, 256, 0, stream>>>(resp, cval, cpos);
  topk_kernel<<<16, 256, 0, stream>>>(cval, cpos, sd, pcorn);
  softplus_kernel<<<576, 256, 0, stream>>>((const float4*)sd, psoft);
  prep_desc_kernel<<<8192, 256, 0, stream>>>(desc, descF8, invn);
  gemm_relu_kernel<<<2176, 256, 0, stream>>>(descF8, invn, pgemm);
  finalize_kernel<<<1, 256, 0, stream>>>(psoft, pcorn, pgemm, out);
}

// Round 6
// 183.029 us; speedup vs baseline: 1.2889x; 1.2889x over previous
//
#include <hip/hip_runtime.h>

#define H 384
#define W 384
#define HWSZ (H * W)
#define NB 16
#define ND 2048
#define DD 256

// workspace byte offsets (all 256-aligned)
#define OFF_RESP  256
#define OFF_CVAL  9437440
#define OFF_CPOS  9584896
#define OFF_DESCB 9732352     // fp8 descriptors: 16*2048*256 = 8.4 MB
#define OFF_INV   26509568
#define OFF_PSOFT 26640640    // 576 floats
#define OFF_PGEMM 26643200    // 2176 floats
#define OFF_PCORN 26652160    // 16 floats

__device__ __forceinline__ int clampi(int v) { return v < 0 ? 0 : (v > 383 ? 383 : v); }
__device__ __forceinline__ int refl(int v) { return v < 0 ? -v : (v >= 384 ? 766 - v : v); }

// fp32 -> OCP e4m3fn with RNE (software; subnormals exact, clamp to 448).
// Layout: [s:1][eeee:4][mmm:3] -> s<<7 | e<<3 | m.
__device__ __forceinline__ unsigned f2e4m3(float x) {
  float a = fabsf(x);
  unsigned s = (__float_as_uint(x) >> 31) << 7;
  if (a >= 448.f) return s | 0x7E;
  if (a < 0.015625f) {                    // subnormal region, unit 2^-9
    int m = (int)rintf(a * 512.f);
    return s | (unsigned)m;
  }
  unsigned u = __float_as_uint(a);
  u += 0x7FFFF + ((u >> 20) & 1);         // RNE to 3 mantissa bits
  unsigned e = (u >> 23) - 120;           // rebias 127->7
  unsigned m = (u >> 20) & 7;
  return s | (e << 3) | m;
}

// ---------------------------------------------------------------------------
// Fused: grayscale -> sobel(edge pad) -> products -> separable 7x7 gauss
// (reflect pad) -> GFTT min-eigenvalue response. One 32x32 output tile/block.
// ---------------------------------------------------------------------------
__global__ __launch_bounds__(256) void resp_kernel(const float* __restrict__ imgs,
                                                   float* __restrict__ resp) {
  const float GW[7] = {0.0044330482f, 0.0540055826f, 0.2420362294f, 0.3990502160f,
                       0.2420362294f, 0.0540055826f, 0.0044330482f};
  __shared__ float gl[40][41];
  __shared__ float p0[38][39], p1[38][39], p2[38][39];
  __shared__ float t0[38][33], t1[38][33], t2[38][33];

  int bid = blockIdx.x;
  int b = bid / 144;
  int t = bid % 144;
  int Y0 = (t / 12) * 32, X0 = (t % 12) * 32;
  const float* ib = imgs + (size_t)b * 3 * HWSZ;

  for (int i = threadIdx.x; i < 1600; i += 256) {
    int r = i / 40, c = i % 40;
    int gy = clampi(Y0 - 4 + r), gx = clampi(X0 - 4 + c);
    const float* p = ib + gy * W + gx;
    gl[r][c] = 0.299f * p[0] + 0.587f * p[HWSZ] + 0.114f * p[2 * HWSZ];
  }
  __syncthreads();

  for (int i = threadIdx.x; i < 1444; i += 256) {
    int r = i / 38, c = i % 38;
    int py = refl(Y0 - 3 + r), px = refl(X0 - 3 + c);
    int ym = clampi(py - 1) - (Y0 - 4), y0 = py - (Y0 - 4), yp = clampi(py + 1) - (Y0 - 4);
    int xm = clampi(px - 1) - (X0 - 4), x0 = px - (X0 - 4), xp = clampi(px + 1) - (X0 - 4);
    float a = gl[ym][xm], bb = gl[ym][x0], cc = gl[ym][xp];
    float d = gl[y0][xm], e = gl[y0][xp];
    float f = gl[yp][xm], g = gl[yp][x0], h = gl[yp][xp];
    float dx = 0.125f * ((cc - a) + 2.f * (e - d) + (h - f));
    float dy = 0.125f * ((f - a) + 2.f * (g - bb) + (h - cc));
    p0[r][c] = dx * dx;
    p1[r][c] = dy * dy;
    p2[r][c] = dx * dy;
  }
  __syncthreads();

  for (int i = threadIdx.x; i < 1216; i += 256) {
    int r = i / 32, c = i % 32;
    float s0 = 0.f, s1 = 0.f, s2 = 0.f;
#pragma unroll
    for (int j = 0; j < 7; j++) {
      s0 += GW[j] * p0[r][c + j];
      s1 += GW[j] * p1[r][c + j];
      s2 += GW[j] * p2[r][c + j];
    }
    t0[r][c] = s0; t1[r][c] = s1; t2[r][c] = s2;
  }
  __syncthreads();

  for (int i = threadIdx.x; i < 1024; i += 256) {
    int r = i / 32, c = i % 32;
    float s0 = 0.f, s1 = 0.f, s2 = 0.f;
#pragma unroll
    for (int j = 0; j < 7; j++) {
      s0 += GW[j] * t0[r + j][c];
      s1 += GW[j] * t1[r + j][c];
      s2 += GW[j] * t2[r + j][c];
    }
    float tr = s0 + s1;
    float det = s0 * s1 - s2 * s2;
    float disc = tr * tr - 4.f * det;
    float rv = 0.5f * (tr - sqrtf(fabsf(disc)));
    resp[(size_t)b * HWSZ + (Y0 + r) * W + (X0 + c)] = rv;
  }
}

// ---------------------------------------------------------------------------
// 5x5 NMS (-inf border) + per-8x8-block max candidate extraction.
// ---------------------------------------------------------------------------
__global__ __launch_bounds__(256) void nms_kernel(const float* __restrict__ resp,
                                                  float* __restrict__ cval,
                                                  unsigned* __restrict__ cpos) {
  __shared__ float rl[68][69];
  __shared__ float nl[64][65];
  int bid = blockIdx.x;
  int b = bid / 36;
  int t = bid % 36;
  int Y0 = (t / 6) * 64, X0 = (t % 6) * 64;
  const float* rb = resp + (size_t)b * HWSZ;

  for (int i = threadIdx.x; i < 68 * 68; i += 256) {
    int r = i / 68, c = i % 68;
    int gy = Y0 - 2 + r, gx = X0 - 2 + c;
    float v = -INFINITY;
    if (gy >= 0 && gy < H && gx >= 0 && gx < W) v = rb[gy * W + gx];
    rl[r][c] = v;
  }
  __syncthreads();

  for (int i = threadIdx.x; i < 4096; i += 256) {
    int r = i / 64, c = i % 64;
    float m = -INFINITY;
#pragma unroll
    for (int dr = 0; dr < 5; dr++)
#pragma unroll
      for (int dc = 0; dc < 5; dc++) m = fmaxf(m, rl[r + dr][c + dc]);
    float v = rl[r + 2][c + 2];
    nl[r][c] = (v == m) ? v : 0.f;
  }
  __syncthreads();

  if (threadIdx.x < 64) {
    int bi = threadIdx.x / 8, bj = threadIdx.x % 8;
    float bv = 0.f;
    unsigned bp = 0;
    for (int rr = 0; rr < 8; rr++)
      for (int cc = 0; cc < 8; cc++) {
        float v = nl[bi * 8 + rr][bj * 8 + cc];
        if (v > bv) { bv = v; bp = (unsigned)((Y0 + bi * 8 + rr) * W + (X0 + bj * 8 + cc)); }
      }
    int ci = b * 2304 + (Y0 / 8 + bi) * 48 + (X0 / 8 + bj);
    cval[ci] = bv;
    cpos[ci] = bp;
  }
}

// ---------------------------------------------------------------------------
// Per-batch top-200 via byte-wise radix-select.
// ---------------------------------------------------------------------------
__global__ __launch_bounds__(256) void topk_kernel(const float* __restrict__ cval,
                                                   const unsigned* __restrict__ cpos,
                                                   const float* __restrict__ sd,
                                                   float* __restrict__ pcorn) {
  __shared__ int hist[256];
  __shared__ int pick[2];
  __shared__ unsigned eqpos[256];
  __shared__ int eqcnt;
  __shared__ float rf[4];
  __shared__ int ri[4];

  int b = blockIdx.x;
  int t = threadIdx.x;
  int lane = t & 63;

  unsigned bits[9], pos[9];
#pragma unroll
  for (int q = 0; q < 9; q++) {
    int i = t + q * 256;
    unsigned vb = 0, p = 0;
    if (i < 2304) {
      float v = cval[b * 2304 + i];
      if (v > 0.f) { vb = __float_as_uint(v); p = cpos[b * 2304 + i]; }
    }
    bits[q] = vb; pos[q] = p;
  }

  int P = 0;
#pragma unroll
  for (int q = 0; q < 9; q++) P += (bits[q] != 0u);
  for (int off = 32; off; off >>= 1) P += __shfl_down(P, off, 64);
  if (lane == 0) ri[t >> 6] = P;
  __syncthreads();
  int Ptot = ri[0] + ri[1] + ri[2] + ri[3];
  if (Ptot == 0) { if (t == 0) pcorn[b] = 0.f; return; }
  int K = Ptot < 200 ? Ptot : 200;

  unsigned prefix = 0;
  int krem = K;
  for (int shift = 24; shift >= 0; shift -= 8) {
    hist[t] = 0;
    __syncthreads();
#pragma unroll
    for (int q = 0; q < 9; q++) {
      if (bits[q] != 0u &&
          (shift == 24 || (bits[q] >> (shift + 8)) == (prefix >> (shift + 8))))
        atomicAdd(&hist[(bits[q] >> shift) & 0xFF], 1);
    }
    __syncthreads();
    if (t < 64) {
      int h0 = hist[4 * t], h1 = hist[4 * t + 1], h2 = hist[4 * t + 2], h3 = hist[4 * t + 3];
      int tot = h0 + h1 + h2 + h3;
      int acc = tot;
      for (int d = 1; d < 64; d <<= 1) {
        int o = __shfl_down(acc, d, 64);
        if (t + d < 64) acc += o;
      }
      int excl = acc - tot;
      int G3 = excl, G2 = excl + h3, G1 = excl + h3 + h2, G0 = excl + h3 + h2 + h1;
      if (G0 < krem && G0 + h0 >= krem) { pick[0] = 4 * t;     pick[1] = G0; }
      if (G1 < krem && G1 + h1 >= krem) { pick[0] = 4 * t + 1; pick[1] = G1; }
      if (G2 < krem && G2 + h2 >= krem) { pick[0] = 4 * t + 2; pick[1] = G2; }
      if (G3 < krem && G3 + h3 >= krem) { pick[0] = 4 * t + 3; pick[1] = G3; }
    }
    __syncthreads();
    prefix |= ((unsigned)pick[0]) << shift;
    krem -= pick[1];
    __syncthreads();
  }

  if (t == 0) eqcnt = 0;
  __syncthreads();
  float s = 0.f;
#pragma unroll
  for (int q = 0; q < 9; q++) {
    if (bits[q] > prefix) s += sd[(size_t)b * HWSZ + pos[q]];
    else if (bits[q] != 0u && bits[q] == prefix) {
      int idx = atomicAdd(&eqcnt, 1);
      if (idx < 256) eqpos[idx] = pos[q];
    }
  }
  __syncthreads();
  int m = eqcnt;
  if (m <= krem) {
    if (t < m) s += sd[(size_t)b * HWSZ + eqpos[t]];
  } else {
    int mm = m < 256 ? m : 256;
    if (t < mm) {
      unsigned p = eqpos[t];
      int rank = 0;
      for (int u = 0; u < mm; u++) rank += (eqpos[u] < p);
      if (rank < krem) s += sd[(size_t)b * HWSZ + p];
    }
  }
  for (int off = 32; off; off >>= 1) s += __shfl_down(s, off, 64);
  if (lane == 0) rf[t >> 6] = s;
  __syncthreads();
  if (t == 0) pcorn[b] = rf[0] + rf[1] + rf[2] + rf[3];
}

// ---------------------------------------------------------------------------
// Sum of softplus(scores_dense) -> per-block partials.
// ---------------------------------------------------------------------------
__global__ __launch_bounds__(256) void softplus_kernel(const float4* __restrict__ sd,
                                                       float* __restrict__ psoft) {
  __shared__ float r4[4];
  float s = 0.f;
  int base = blockIdx.x * 256 + threadIdx.x;
#pragma unroll
  for (int it = 0; it < 4; it++) {
    float4 v = sd[base + it * 147456];
    s += fmaxf(v.x, 0.f) + log1pf(expf(-fabsf(v.x))) +
         fmaxf(v.y, 0.f) + log1pf(expf(-fabsf(v.y))) +
         fmaxf(v.z, 0.f) + log1pf(expf(-fabsf(v.z))) +
         fmaxf(v.w, 0.f) + log1pf(expf(-fabsf(v.w)));
  }
  for (int off = 32; off; off >>= 1) s += __shfl_down(s, off, 64);
  if ((threadIdx.x & 63) == 0) r4[threadIdx.x >> 6] = s;
  __syncthreads();
  if (threadIdx.x == 0) psoft[blockIdx.x] = r4[0] + r4[1] + r4[2] + r4[3];
}

// ---------------------------------------------------------------------------
// Descriptor prep: fp32 -> fp8 e4m3 + per-row inverse norm (fp32 norms).
// ---------------------------------------------------------------------------
__global__ __launch_bounds__(256) void prep_desc_kernel(const float* __restrict__ desc,
                                                        unsigned char* __restrict__ descF8,
                                                        float* __restrict__ invn) {
  int wave = threadIdx.x >> 6, lane = threadIdx.x & 63;
  int row = blockIdx.x * 4 + wave;
  const float4* src = (const float4*)(desc + (size_t)row * DD);
  float4 v = src[lane];
  unsigned pk = f2e4m3(v.x) | (f2e4m3(v.y) << 8) | (f2e4m3(v.z) << 16) | (f2e4m3(v.w) << 24);
  ((unsigned*)(descF8 + (size_t)row * DD))[lane] = pk;
  float ss = v.x * v.x + v.y * v.y + v.z * v.z + v.w * v.w;
  for (int off = 32; off; off >>= 1) ss += __shfl_down(ss, off, 64);
  if (lane == 0) invn[row] = 1.f / fmaxf(sqrtf(ss), 1e-4f);
}

// ---------------------------------------------------------------------------
// Symmetric batched GEMM (A·A^T) in fp8 e4m3 with fused relu-sum epilogue.
// 128x128 tiles, BK=128, 16x16x32 fp8 MFMA, global_load_lds width-16.
//
// LDS bank-swizzle (R5 fix): row stride is 128 B == 32 banks, so unswizzled
// fragment reads put all 16 rm-lanes of a kq-group on the same 2 banks ->
// 16-way conflict (SQ_LDS_BANK_CONFLICT 3.34e7 ~= 54us/CU). global_load_lds
// pins LDS writes to base+lane*16, so we swizzle on the GLOBAL SOURCE side:
// lane (lrow,lc) stages logical 16B-chunk (lc^lrow); readers map logical
// chunk c of row r to physical chunk c^(r&7). K-permutation is harmless in
// a Gram matrix (both operands permute identically).
// ---------------------------------------------------------------------------
typedef float f32x4 __attribute__((ext_vector_type(4)));

__device__ __forceinline__ void load_lds16(const void* g, void* l) {
  __builtin_amdgcn_global_load_lds((const __attribute__((address_space(1))) void*)g,
                                   (__attribute__((address_space(3))) void*)l, 16, 0, 0);
}

__global__ __launch_bounds__(256) void gemm_relu_kernel(const unsigned char* __restrict__ descF8,
                                                        const float* __restrict__ invn,
                                                        float* __restrict__ pgemm) {
  int bx = blockIdx.x;
  int batch = bx / 136;
  int rem = bx % 136;
  int ti = 0, rowlen = 16;
  while (rem >= rowlen) { rem -= rowlen; rowlen--; ti++; }
  int tj = ti + rem;

  const unsigned char* Ab = descF8 + (size_t)batch * ND * DD;
  const float* inv = invn + batch * ND;
  int I0 = ti * 128, J0 = tj * 128;

  __shared__ char lA[128 * 128];   // 16 KB: 128 rows x 128 bytes (BK=128 fp8)
  __shared__ char lB[128 * 128];
  __shared__ float r4[4];

  int tid = threadIdx.x;
  int wave = tid >> 6, lane = tid & 63;
  int rm = lane & 15, kq = lane >> 4;
  int wr = wave >> 1, wc = wave & 1;
  int lrow = lane >> 3;
  int lcolb = ((lane & 7) ^ lrow) << 4;   // swizzled source column (bytes)
  int cx = rm & 7;                        // read-side swizzle key (uniform over m,n)

  f32x4 accf[4][4];
#pragma unroll
  for (int m = 0; m < 4; m++)
#pragma unroll
    for (int n = 0; n < 4; n++) accf[m][n] = (f32x4){0.f, 0.f, 0.f, 0.f};

  for (int k0 = 0; k0 < DD; k0 += 128) {
#pragma unroll
    for (int q = 0; q < 4; q++) {
      int chunk = wave * 4 + q;   // covers rows chunk*8 .. chunk*8+7 (128B each)
      load_lds16(Ab + (size_t)(I0 + chunk * 8 + lrow) * DD + k0 + lcolb, lA + chunk * 1024);
      load_lds16(Ab + (size_t)(J0 + chunk * 8 + lrow) * DD + k0 + lcolb, lB + chunk * 1024);
    }
    __syncthreads();
#pragma unroll
    for (int kk = 0; kk < 128; kk += 32) {
      long af[4], bfr[4];
      int koff = kk + kq * 8;
      int pcol = ((((koff >> 4) ^ cx) << 4) | (koff & 8));  // physical column
#pragma unroll
      for (int m = 0; m < 4; m++)
        af[m] = *reinterpret_cast<const long*>(lA + (wr * 64 + m * 16 + rm) * 128 + pcol);
#pragma unroll
      for (int n = 0; n < 4; n++)
        bfr[n] = *reinterpret_cast<const long*>(lB + (wc * 64 + n * 16 + rm) * 128 + pcol);
#pragma unroll
      for (int m = 0; m < 4; m++)
#pragma unroll
        for (int n = 0; n < 4; n++)
          accf[m][n] = __builtin_amdgcn_mfma_f32_16x16x32_fp8_fp8(af[m], bfr[n], accf[m][n], 0, 0, 0);
    }
    __syncthreads();
  }

  float wgt = (ti == tj) ? 1.f : 2.f;
  float invC[4];
#pragma unroll
  for (int n = 0; n < 4; n++) invC[n] = inv[J0 + wc * 64 + n * 16 + rm];
  float psum = 0.f;
#pragma unroll
  for (int m = 0; m < 4; m++) {
#pragma unroll
    for (int r = 0; r < 4; r++) {
      float invR = inv[I0 + wr * 64 + m * 16 + kq * 4 + r];
#pragma unroll
      for (int n = 0; n < 4; n++) psum += fmaxf(accf[m][n][r] * invR * invC[n], 0.f);
    }
  }
  psum *= wgt;
  for (int off = 32; off; off >>= 1) psum += __shfl_down(psum, off, 64);
  if (lane == 0) r4[wave] = psum;
  __syncthreads();
  if (tid == 0) pgemm[bx] = r4[0] + r4[1] + r4[2] + r4[3];
}

// ---------------------------------------------------------------------------
// Final reduction over all partial arrays -> out[0].
// ---------------------------------------------------------------------------
__global__ __launch_bounds__(256) void finalize_kernel(const float* __restrict__ psoft,
                                                       const float* __restrict__ pcorn,
                                                       const float* __restrict__ pgemm,
                                                       float* __restrict__ out) {
  __shared__ float r4[4];
  float bce = 0.f;
  for (int i = threadIdx.x; i < 576; i += 256) bce += psoft[i];
  if (threadIdx.x < 16) bce -= pcorn[threadIdx.x];
  float g = 0.f;
  for (int i = threadIdx.x; i < 2176; i += 256) g += pgemm[i];
  float t = bce * (1.f / 2359296.f) + g * (1.f / 67108864.f);
  for (int off = 32; off; off >>= 1) t += __shfl_down(t, off, 64);
  if ((threadIdx.x & 63) == 0) r4[threadIdx.x >> 6] = t;
  __syncthreads();
  if (threadIdx.x == 0) out[0] = r4[0] + r4[1] + r4[2] + r4[3];
}

extern "C" void kernel_launch(void* const* d_in, const int* in_sizes, int n_in,
                              void* d_out, int out_size, void* d_ws, size_t ws_size,
                              hipStream_t stream) {
  (void)in_sizes; (void)n_in; (void)out_size; (void)ws_size;
  const float* desc = (const float*)d_in[0];
  const float* sd = (const float*)d_in[2];
  const float* imgs = (const float*)d_in[3];
  float* out = (float*)d_out;

  char* w = (char*)d_ws;
  float* resp = (float*)(w + OFF_RESP);
  float* cval = (float*)(w + OFF_CVAL);
  unsigned* cpos = (unsigned*)(w + OFF_CPOS);
  unsigned char* descF8 = (unsigned char*)(w + OFF_DESCB);
  float* invn = (float*)(w + OFF_INV);
  float* psoft = (float*)(w + OFF_PSOFT);
  float* pgemm = (float*)(w + OFF_PGEMM);
  float* pcorn = (float*)(w + OFF_PCORN);

  resp_kernel<<<2304, 256, 0, stream>>>(imgs, resp);
  nms_kernel<<<576, 256, 0, stream>>>(resp, cval, cpos);
  topk_kernel<<<16, 256, 0, stream>>>(cval, cpos, sd, pcorn);
  softplus_kernel<<<576, 256, 0, stream>>>((const float4*)sd, psoft);
  prep_desc_kernel<<<8192, 256, 0, stream>>>(desc, descF8, invn);
  gemm_relu_kernel<<<2176, 256, 0, stream>>>(descF8, invn, pgemm);
  finalize_kernel<<<1, 256, 0, stream>>>(psoft, pcorn, pgemm, out);
}

// Round 7
// 160.025 us; speedup vs baseline: 1.4742x; 1.1438x over previous
//
#include <hip/hip_runtime.h>

#define H 384
#define W 384
#define HWSZ (H * W)
#define NB 16
#define ND 2048
#define DD 256

// workspace byte offsets (all 256-aligned)
#define OFF_RESP  256
#define OFF_CVAL  9437440
#define OFF_CPOS  9584896
#define OFF_DESCB 9732352     // fp8 descriptors: 16*2048*256 = 8.4 MB
#define OFF_INV   26509568
#define OFF_PSOFT 26640640    // 576 floats
#define OFF_PGEMM 26643200    // 2176 floats
#define OFF_PCORN 26652160    // 16 floats

__device__ __forceinline__ int clampi(int v) { return v < 0 ? 0 : (v > 383 ? 383 : v); }
__device__ __forceinline__ int refl(int v) { return v < 0 ? -v : (v >= 384 ? 766 - v : v); }

// fp32 -> OCP e4m3fn with RNE. Layout: [s:1][eeee:4][mmm:3] -> s<<7 | e<<3 | m.
__device__ __forceinline__ unsigned f2e4m3(float x) {
  float a = fabsf(x);
  unsigned s = (__float_as_uint(x) >> 31) << 7;
  if (a >= 448.f) return s | 0x7E;
  if (a < 0.015625f) {
    int m = (int)rintf(a * 512.f);
    return s | (unsigned)m;
  }
  unsigned u = __float_as_uint(a);
  u += 0x7FFFF + ((u >> 20) & 1);
  unsigned e = (u >> 23) - 120;
  unsigned m = (u >> 20) & 7;
  return s | (e << 3) | m;
}

typedef float f32x4 __attribute__((ext_vector_type(4)));

__device__ __forceinline__ void load_lds16(const void* g, void* l) {
  __builtin_amdgcn_global_load_lds((const __attribute__((address_space(1))) void*)g,
                                   (__attribute__((address_space(3))) void*)l, 16, 0, 0);
}

// ---------------------------------------------------------------------------
// STAGE 1: resp (blocks 0..2303) || prep_desc (blocks 2304..10495).
// Two independent chains fused into one dispatch for concurrency (stream
// order would otherwise serialize them).
// ---------------------------------------------------------------------------
__global__ __launch_bounds__(256) void stage1_kernel(const float* __restrict__ imgs,
                                                     float* __restrict__ resp,
                                                     const float* __restrict__ desc,
                                                     unsigned char* __restrict__ descF8,
                                                     float* __restrict__ invn) {
  __shared__ float gl[40][41];
  __shared__ float p0[38][39], p1[38][39], p2[38][39];
  __shared__ float t0[38][33], t1[38][33], t2[38][33];

  if (blockIdx.x >= 2304) {
    // ---- prep_desc: fp32 -> fp8 e4m3 + per-row inverse norm ----
    int wave = threadIdx.x >> 6, lane = threadIdx.x & 63;
    int row = (blockIdx.x - 2304) * 4 + wave;
    const float4* src = (const float4*)(desc + (size_t)row * DD);
    float4 v = src[lane];
    unsigned pk = f2e4m3(v.x) | (f2e4m3(v.y) << 8) | (f2e4m3(v.z) << 16) | (f2e4m3(v.w) << 24);
    ((unsigned*)(descF8 + (size_t)row * DD))[lane] = pk;
    float ss = v.x * v.x + v.y * v.y + v.z * v.z + v.w * v.w;
    for (int off = 32; off; off >>= 1) ss += __shfl_down(ss, off, 64);
    if (lane == 0) invn[row] = 1.f / fmaxf(sqrtf(ss), 1e-4f);
    return;
  }

  // ---- resp: gray -> sobel(edge) -> products -> 7x7 gauss(reflect) -> GFTT ----
  const float GW[7] = {0.0044330482f, 0.0540055826f, 0.2420362294f, 0.3990502160f,
                       0.2420362294f, 0.0540055826f, 0.0044330482f};
  int bid = blockIdx.x;
  int b = bid / 144;
  int t = bid % 144;
  int Y0 = (t / 12) * 32, X0 = (t % 12) * 32;
  const float* ib = imgs + (size_t)b * 3 * HWSZ;

  for (int i = threadIdx.x; i < 1600; i += 256) {
    int r = i / 40, c = i % 40;
    int gy = clampi(Y0 - 4 + r), gx = clampi(X0 - 4 + c);
    const float* p = ib + gy * W + gx;
    gl[r][c] = 0.299f * p[0] + 0.587f * p[HWSZ] + 0.114f * p[2 * HWSZ];
  }
  __syncthreads();

  for (int i = threadIdx.x; i < 1444; i += 256) {
    int r = i / 38, c = i % 38;
    int py = refl(Y0 - 3 + r), px = refl(X0 - 3 + c);
    int ym = clampi(py - 1) - (Y0 - 4), y0 = py - (Y0 - 4), yp = clampi(py + 1) - (Y0 - 4);
    int xm = clampi(px - 1) - (X0 - 4), x0 = px - (X0 - 4), xp = clampi(px + 1) - (X0 - 4);
    float a = gl[ym][xm], bb = gl[ym][x0], cc = gl[ym][xp];
    float d = gl[y0][xm], e = gl[y0][xp];
    float f = gl[yp][xm], g = gl[yp][x0], h = gl[yp][xp];
    float dx = 0.125f * ((cc - a) + 2.f * (e - d) + (h - f));
    float dy = 0.125f * ((f - a) + 2.f * (g - bb) + (h - cc));
    p0[r][c] = dx * dx;
    p1[r][c] = dy * dy;
    p2[r][c] = dx * dy;
  }
  __syncthreads();

  for (int i = threadIdx.x; i < 1216; i += 256) {
    int r = i / 32, c = i % 32;
    float s0 = 0.f, s1 = 0.f, s2 = 0.f;
#pragma unroll
    for (int j = 0; j < 7; j++) {
      s0 += GW[j] * p0[r][c + j];
      s1 += GW[j] * p1[r][c + j];
      s2 += GW[j] * p2[r][c + j];
    }
    t0[r][c] = s0; t1[r][c] = s1; t2[r][c] = s2;
  }
  __syncthreads();

  for (int i = threadIdx.x; i < 1024; i += 256) {
    int r = i / 32, c = i % 32;
    float s0 = 0.f, s1 = 0.f, s2 = 0.f;
#pragma unroll
    for (int j = 0; j < 7; j++) {
      s0 += GW[j] * t0[r + j][c];
      s1 += GW[j] * t1[r + j][c];
      s2 += GW[j] * t2[r + j][c];
    }
    float tr = s0 + s1;
    float det = s0 * s1 - s2 * s2;
    float disc = tr * tr - 4.f * det;
    float rv = 0.5f * (tr - sqrtf(fabsf(disc)));
    resp[(size_t)b * HWSZ + (Y0 + r) * W + (X0 + c)] = rv;
  }
}

// ---------------------------------------------------------------------------
// STAGE 2: nms (blocks 0..575) || softplus partials (blocks 576..1151).
// ---------------------------------------------------------------------------
__global__ __launch_bounds__(256) void stage2_kernel(const float* __restrict__ resp,
                                                     float* __restrict__ cval,
                                                     unsigned* __restrict__ cpos,
                                                     const float4* __restrict__ sd4,
                                                     float* __restrict__ psoft) {
  __shared__ float rl[68][69];
  __shared__ float nl[64][65];
  __shared__ float r4[4];

  if (blockIdx.x >= 576) {
    // ---- softplus partial sums ----
    int sb = blockIdx.x - 576;
    float s = 0.f;
    int base = sb * 256 + threadIdx.x;
#pragma unroll
    for (int it = 0; it < 4; it++) {
      float4 v = sd4[base + it * 147456];
      s += fmaxf(v.x, 0.f) + log1pf(expf(-fabsf(v.x))) +
           fmaxf(v.y, 0.f) + log1pf(expf(-fabsf(v.y))) +
           fmaxf(v.z, 0.f) + log1pf(expf(-fabsf(v.z))) +
           fmaxf(v.w, 0.f) + log1pf(expf(-fabsf(v.w)));
    }
    for (int off = 32; off; off >>= 1) s += __shfl_down(s, off, 64);
    if ((threadIdx.x & 63) == 0) r4[threadIdx.x >> 6] = s;
    __syncthreads();
    if (threadIdx.x == 0) psoft[sb] = r4[0] + r4[1] + r4[2] + r4[3];
    return;
  }

  // ---- 5x5 NMS (-inf border) + per-8x8-block max candidate ----
  int bid = blockIdx.x;
  int b = bid / 36;
  int t = bid % 36;
  int Y0 = (t / 6) * 64, X0 = (t % 6) * 64;
  const float* rb = resp + (size_t)b * HWSZ;

  for (int i = threadIdx.x; i < 68 * 68; i += 256) {
    int r = i / 68, c = i % 68;
    int gy = Y0 - 2 + r, gx = X0 - 2 + c;
    float v = -INFINITY;
    if (gy >= 0 && gy < H && gx >= 0 && gx < W) v = rb[gy * W + gx];
    rl[r][c] = v;
  }
  __syncthreads();

  for (int i = threadIdx.x; i < 4096; i += 256) {
    int r = i / 64, c = i % 64;
    float m = -INFINITY;
#pragma unroll
    for (int dr = 0; dr < 5; dr++)
#pragma unroll
      for (int dc = 0; dc < 5; dc++) m = fmaxf(m, rl[r + dr][c + dc]);
    float v = rl[r + 2][c + 2];
    nl[r][c] = (v == m) ? v : 0.f;
  }
  __syncthreads();

  if (threadIdx.x < 64) {
    int bi = threadIdx.x / 8, bj = threadIdx.x % 8;
    float bv = 0.f;
    unsigned bp = 0;
    for (int rr = 0; rr < 8; rr++)
      for (int cc = 0; cc < 8; cc++) {
        float v = nl[bi * 8 + rr][bj * 8 + cc];
        if (v > bv) { bv = v; bp = (unsigned)((Y0 + bi * 8 + rr) * W + (X0 + bj * 8 + cc)); }
      }
    int ci = b * 2304 + (Y0 / 8 + bi) * 48 + (X0 / 8 + bj);
    cval[ci] = bv;
    cpos[ci] = bp;
  }
}

// ---------------------------------------------------------------------------
// STAGE 3: topk radix-select (blocks 0..15, scheduled first so its latency
// hides under gemm) || fp8 Gram-GEMM relu-sum (blocks 16..2191).
// ---------------------------------------------------------------------------
__global__ __launch_bounds__(256) void stage3_kernel(const float* __restrict__ cval,
                                                     const unsigned* __restrict__ cpos,
                                                     const float* __restrict__ sd,
                                                     float* __restrict__ pcorn,
                                                     const unsigned char* __restrict__ descF8,
                                                     const float* __restrict__ invn,
                                                     float* __restrict__ pgemm) {
  // gemm shared
  __shared__ char lA[128 * 128];
  __shared__ char lB[128 * 128];
  __shared__ float r4[4];
  // topk shared
  __shared__ int hist[256];
  __shared__ int pick[2];
  __shared__ unsigned eqpos[256];
  __shared__ int eqcnt;
  __shared__ int ri[4];

  if (blockIdx.x < 16) {
    // ---- per-batch top-200 radix-select -> sum sd at corners ----
    int b = blockIdx.x;
    int t = threadIdx.x;
    int lane = t & 63;

    unsigned bits[9], pos[9];
#pragma unroll
    for (int q = 0; q < 9; q++) {
      int i = t + q * 256;
      unsigned vb = 0, p = 0;
      if (i < 2304) {
        float v = cval[b * 2304 + i];
        if (v > 0.f) { vb = __float_as_uint(v); p = cpos[b * 2304 + i]; }
      }
      bits[q] = vb; pos[q] = p;
    }

    int P = 0;
#pragma unroll
    for (int q = 0; q < 9; q++) P += (bits[q] != 0u);
    for (int off = 32; off; off >>= 1) P += __shfl_down(P, off, 64);
    if (lane == 0) ri[t >> 6] = P;
    __syncthreads();
    int Ptot = ri[0] + ri[1] + ri[2] + ri[3];
    if (Ptot == 0) { if (t == 0) pcorn[b] = 0.f; return; }
    int K = Ptot < 200 ? Ptot : 200;

    unsigned prefix = 0;
    int krem = K;
    for (int shift = 24; shift >= 0; shift -= 8) {
      hist[t] = 0;
      __syncthreads();
#pragma unroll
      for (int q = 0; q < 9; q++) {
        if (bits[q] != 0u &&
            (shift == 24 || (bits[q] >> (shift + 8)) == (prefix >> (shift + 8))))
          atomicAdd(&hist[(bits[q] >> shift) & 0xFF], 1);
      }
      __syncthreads();
      if (t < 64) {
        int h0 = hist[4 * t], h1 = hist[4 * t + 1], h2 = hist[4 * t + 2], h3 = hist[4 * t + 3];
        int tot = h0 + h1 + h2 + h3;
        int acc = tot;
        for (int d = 1; d < 64; d <<= 1) {
          int o = __shfl_down(acc, d, 64);
          if (t + d < 64) acc += o;
        }
        int excl = acc - tot;
        int G3 = excl, G2 = excl + h3, G1 = excl + h3 + h2, G0 = excl + h3 + h2 + h1;
        if (G0 < krem && G0 + h0 >= krem) { pick[0] = 4 * t;     pick[1] = G0; }
        if (G1 < krem && G1 + h1 >= krem) { pick[0] = 4 * t + 1; pick[1] = G1; }
        if (G2 < krem && G2 + h2 >= krem) { pick[0] = 4 * t + 2; pick[1] = G2; }
        if (G3 < krem && G3 + h3 >= krem) { pick[0] = 4 * t + 3; pick[1] = G3; }
      }
      __syncthreads();
      prefix |= ((unsigned)pick[0]) << shift;
      krem -= pick[1];
      __syncthreads();
    }

    if (t == 0) eqcnt = 0;
    __syncthreads();
    float s = 0.f;
#pragma unroll
    for (int q = 0; q < 9; q++) {
      if (bits[q] > prefix) s += sd[(size_t)b * HWSZ + pos[q]];
      else if (bits[q] != 0u && bits[q] == prefix) {
        int idx = atomicAdd(&eqcnt, 1);
        if (idx < 256) eqpos[idx] = pos[q];
      }
    }
    __syncthreads();
    int m = eqcnt;
    if (m <= krem) {
      if (t < m) s += sd[(size_t)b * HWSZ + eqpos[t]];
    } else {
      int mm = m < 256 ? m : 256;
      if (t < mm) {
        unsigned p = eqpos[t];
        int rank = 0;
        for (int u = 0; u < mm; u++) rank += (eqpos[u] < p);
        if (rank < krem) s += sd[(size_t)b * HWSZ + p];
      }
    }
    for (int off = 32; off; off >>= 1) s += __shfl_down(s, off, 64);
    if (lane == 0) r4[t >> 6] = s;
    __syncthreads();
    if (t == 0) pcorn[b] = r4[0] + r4[1] + r4[2] + r4[3];
    return;
  }

  // ---- fp8 Gram-GEMM with relu-sum epilogue; swizzled LDS (see R6) ----
  int bx = blockIdx.x - 16;
  int batch = bx / 136;
  int rem = bx % 136;
  int ti = 0, rowlen = 16;
  while (rem >= rowlen) { rem -= rowlen; rowlen--; ti++; }
  int tj = ti + rem;

  const unsigned char* Ab = descF8 + (size_t)batch * ND * DD;
  const float* inv = invn + batch * ND;
  int I0 = ti * 128, J0 = tj * 128;

  int tid = threadIdx.x;
  int wave = tid >> 6, lane = tid & 63;
  int rm = lane & 15, kq = lane >> 4;
  int wr = wave >> 1, wc = wave & 1;
  int lrow = lane >> 3;
  int lcolb = ((lane & 7) ^ lrow) << 4;   // swizzled source column (bytes)
  int cx = rm & 7;                        // read-side swizzle key

  f32x4 accf[4][4];
#pragma unroll
  for (int m = 0; m < 4; m++)
#pragma unroll
    for (int n = 0; n < 4; n++) accf[m][n] = (f32x4){0.f, 0.f, 0.f, 0.f};

  for (int k0 = 0; k0 < DD; k0 += 128) {
#pragma unroll
    for (int q = 0; q < 4; q++) {
      int chunk = wave * 4 + q;
      load_lds16(Ab + (size_t)(I0 + chunk * 8 + lrow) * DD + k0 + lcolb, lA + chunk * 1024);
      load_lds16(Ab + (size_t)(J0 + chunk * 8 + lrow) * DD + k0 + lcolb, lB + chunk * 1024);
    }
    __syncthreads();
#pragma unroll
    for (int kk = 0; kk < 128; kk += 32) {
      long af[4], bfr[4];
      int koff = kk + kq * 8;
      int pcol = ((((koff >> 4) ^ cx) << 4) | (koff & 8));
#pragma unroll
      for (int m = 0; m < 4; m++)
        af[m] = *reinterpret_cast<const long*>(lA + (wr * 64 + m * 16 + rm) * 128 + pcol);
#pragma unroll
      for (int n = 0; n < 4; n++)
        bfr[n] = *reinterpret_cast<const long*>(lB + (wc * 64 + n * 16 + rm) * 128 + pcol);
#pragma unroll
      for (int m = 0; m < 4; m++)
#pragma unroll
        for (int n = 0; n < 4; n++)
          accf[m][n] = __builtin_amdgcn_mfma_f32_16x16x32_fp8_fp8(af[m], bfr[n], accf[m][n], 0, 0, 0);
    }
    __syncthreads();
  }

  float wgt = (ti == tj) ? 1.f : 2.f;
  float invC[4];
#pragma unroll
  for (int n = 0; n < 4; n++) invC[n] = inv[J0 + wc * 64 + n * 16 + rm];
  float psum = 0.f;
#pragma unroll
  for (int m = 0; m < 4; m++) {
#pragma unroll
    for (int r = 0; r < 4; r++) {
      float invR = inv[I0 + wr * 64 + m * 16 + kq * 4 + r];
#pragma unroll
      for (int n = 0; n < 4; n++) psum += fmaxf(accf[m][n][r] * invR * invC[n], 0.f);
    }
  }
  psum *= wgt;
  for (int off = 32; off; off >>= 1) psum += __shfl_down(psum, off, 64);
  if (lane == 0) r4[wave] = psum;
  __syncthreads();
  if (tid == 0) pgemm[bx] = r4[0] + r4[1] + r4[2] + r4[3];
}

// ---------------------------------------------------------------------------
// STAGE 4: final reduction over all partial arrays -> out[0].
// ---------------------------------------------------------------------------
__global__ __launch_bounds__(256) void finalize_kernel(const float* __restrict__ psoft,
                                                       const float* __restrict__ pcorn,
                                                       const float* __restrict__ pgemm,
                                                       float* __restrict__ out) {
  __shared__ float r4[4];
  float bce = 0.f;
  for (int i = threadIdx.x; i < 576; i += 256) bce += psoft[i];
  if (threadIdx.x < 16) bce -= pcorn[threadIdx.x];
  float g = 0.f;
  for (int i = threadIdx.x; i < 2176; i += 256) g += pgemm[i];
  float t = bce * (1.f / 2359296.f) + g * (1.f / 67108864.f);
  for (int off = 32; off; off >>= 1) t += __shfl_down(t, off, 64);
  if ((threadIdx.x & 63) == 0) r4[threadIdx.x >> 6] = t;
  __syncthreads();
  if (threadIdx.x == 0) out[0] = r4[0] + r4[1] + r4[2] + r4[3];
}

extern "C" void kernel_launch(void* const* d_in, const int* in_sizes, int n_in,
                              void* d_out, int out_size, void* d_ws, size_t ws_size,
                              hipStream_t stream) {
  (void)in_sizes; (void)n_in; (void)out_size; (void)ws_size;
  const float* desc = (const float*)d_in[0];
  const float* sd = (const float*)d_in[2];
  const float* imgs = (const float*)d_in[3];
  float* out = (float*)d_out;

  char* w = (char*)d_ws;
  float* resp = (float*)(w + OFF_RESP);
  float* cval = (float*)(w + OFF_CVAL);
  unsigned* cpos = (unsigned*)(w + OFF_CPOS);
  unsigned char* descF8 = (unsigned char*)(w + OFF_DESCB);
  float* invn = (float*)(w + OFF_INV);
  float* psoft = (float*)(w + OFF_PSOFT);
  float* pgemm = (float*)(w + OFF_PGEMM);
  float* pcorn = (float*)(w + OFF_PCORN);

  stage1_kernel<<<10496, 256, 0, stream>>>(imgs, resp, desc, descF8, invn);
  stage2_kernel<<<1152, 256, 0, stream>>>(resp, cval, cpos, (const float4*)sd, psoft);
  stage3_kernel<<<2192, 256, 0, stream>>>(cval, cpos, sd, pcorn, descF8, invn, pgemm);
  finalize_kernel<<<1, 256, 0, stream>>>(psoft, pcorn, pgemm, out);
}